// Round 6
// baseline (244.307 us; speedup 1.0000x reference)
//
#include <hip/hip_runtime.h>

// VQ-VAE quantizer via MFMA: x[B=128,C=256,H=32,W=32] f32, e[K=512,C=256] f32.
// out[b,c,hw] = e[argmin_k ||z - e_k||^2][c].
//
// score_k = ||e_k||^2 - 2 z.e_k. Dot via bf16 MFMA Dekker split (3 terms:
// zh.eh + zl.eh + zh.el, err ~1e-3), 6 independent accumulator chains/wave.
// A-build (R6): x staged through LDS in 8x16KB chunks via global_load_lds
// (no VGPR destinations -> full memory-level parallelism), then ds_read +
// convert. e-tiles triple-buffered in LDS, ONE s_barrier + counted vmcnt(4)
// per loop iteration. Near-ties (gap < EPS) re-resolved exactly in fp64.
// Output gather fused into the epilogue.

typedef __attribute__((ext_vector_type(8))) short bf16x8;
typedef __attribute__((ext_vector_type(4))) float f32x4;

constexpr int K_EMB = 512;
constexpr int C_DIM = 256;
constexpr int HW    = 1024;
constexpr float EPS_GAP = 0.02f;

// ws layout (bytes)
constexpr size_t WS_EBIAS = 64;                    // f32[512]
constexpr size_t WS_EH    = 4096;                  // bf16 bits [512][256] = 256KB
constexpr size_t WS_EL    = WS_EH + 262144;        // 256KB
constexpr size_t WS_WORK  = WS_EL + 262144 + 524288;

// LDS: 3 x 16KB e-tile buffers | ebias f32[512] | idx int[128] | x-chunk 16KB
constexpr int LDS_TILES = 49152;
constexpr int LDS_EB    = LDS_TILES;           // +2048
constexpr int LDS_IDX   = LDS_TILES + 2048;    // +512
constexpr int LDS_XBUF  = LDS_TILES + 2560;    // +16384 -> 68096 total

__device__ __forceinline__ unsigned short f2bf(float f) {
    unsigned u = __float_as_uint(f);
    return (unsigned short)((u + 0x7FFFu + ((u >> 16) & 1u)) >> 16);
}

// ---- prep: e -> (eH, eL) bf16 planes + exact ebias, zero job counter ----
__global__ __launch_bounds__(256) void prep_e(const float* __restrict__ e,
                                              unsigned short* __restrict__ eH,
                                              unsigned short* __restrict__ eL,
                                              float* __restrict__ ebias,
                                              int* __restrict__ count) {
    const int k = blockIdx.x, c = threadIdx.x;
    if (k == 0 && c == 0) *count = 0;
    float v = e[(size_t)k * C_DIM + c];
    unsigned short h = f2bf(v);
    float hf = __uint_as_float(((unsigned)h) << 16);
    unsigned short l = f2bf(v - hf);
    eH[(size_t)k * C_DIM + c] = h;
    eL[(size_t)k * C_DIM + c] = l;

    __shared__ double red[256];
    red[c] = (double)v * (double)v;
    __syncthreads();
    for (int s = 128; s > 0; s >>= 1) {
        if (c < s) red[c] += red[c + s];
        __syncthreads();
    }
    if (c == 0) ebias[k] = (float)red[0];
}

// ---- stage one 16-code e-tile (hi+lo planes, 16KB) into LDS at bufoff ----
// Swizzle (byte ^= (row&15)<<4) applied on the GLOBAL source address;
// readers apply the same XOR. (R4/R5-verified.)
__device__ __forceinline__ void stage_tile(char* smem, int bufoff, int nt, int w, int lane,
                                           const unsigned short* eH,
                                           const unsigned short* eL) {
#pragma unroll
    for (int s = 0; s < 4; ++s) {
        int q = w * 4 + s;            // 0..15 across the block
        int plane = q >> 3;           // 0 = hi, 1 = lo
        int ip = q & 7;               // 1KB chunk within plane
        int row = ip * 2 + (lane >> 5);
        int co  = (lane & 31) * 16;   // byte offset within row
        const unsigned short* src = (plane ? eL : eH)
            + ((size_t)(nt * 16 + row)) * C_DIM + ((co ^ ((row & 15) << 4)) >> 1);
        char* dst = smem + bufoff + plane * 8192 + ip * 1024;  // wave-uniform
        __builtin_amdgcn_global_load_lds(
            (const __attribute__((address_space(1))) unsigned int*)src,
            (__attribute__((address_space(3))) unsigned int*)dst, 16, 0, 0);
    }
}

// ---- stage one 32-c-row x-chunk (16KB) into LDS: [32 c][128 hw] f32 ----
__device__ __forceinline__ void stage_xchunk(char* xbuf, const float* xb, int c0, int hw0,
                                             int w, int lane) {
#pragma unroll
    for (int q = 0; q < 4; ++q) {
        int Q = w * 4 + q;                 // 0..15 across the block
        int cl = Q * 2 + (lane >> 5);      // 0..31 local c-row
        const float* src = xb + (size_t)(c0 + cl) * HW + hw0 + (lane & 31) * 4;
        char* dst = xbuf + Q * 1024;       // wave-uniform
        __builtin_amdgcn_global_load_lds(
            (const __attribute__((address_space(1))) unsigned int*)src,
            (__attribute__((address_space(3))) unsigned int*)dst, 16, 0, 0);
    }
}

// ---- main: GEMM + in-register argmin + fused output gather ----
__global__ __launch_bounds__(256, 2) void vq_mfma(const float* __restrict__ x,
                                                  const unsigned short* __restrict__ eH,
                                                  const unsigned short* __restrict__ eL,
                                                  const float* __restrict__ ebias,
                                                  const float* __restrict__ e,
                                                  float* __restrict__ out,
                                                  int* __restrict__ count,
                                                  int* __restrict__ worklist,
                                                  int maxjobs) {
    __shared__ __align__(16) char smem[LDS_XBUF + 16384];
    float* eb_lds = (float*)(smem + LDS_EB);
    int* idx_lds  = (int*)(smem + LDS_IDX);
    char* xbuf    = smem + LDS_XBUF;
    const int t = threadIdx.x, lane = t & 63, w = t >> 6;
    const int b = blockIdx.x >> 3;
    const int hw0 = (blockIdx.x & 7) << 7;
    const float* xb = x + (size_t)b * C_DIM * HW;

    // ebias -> LDS (oldest vmem ops; retire at first chunk drain)
    eb_lds[t]       = ebias[t];
    eb_lds[t + 256] = ebias[t + 256];

    // ---- A-build: 8 x-chunks through LDS (global_load_lds = full MLP) ----
    bf16x8 Ah[2][8], Al[2][8];
    stage_xchunk(xbuf, xb, 0, hw0, w, lane);
#pragma unroll 1
    for (int ci = 0; ci < 8; ++ci) {
        asm volatile("s_waitcnt vmcnt(0)" ::: "memory");
        __builtin_amdgcn_s_barrier();
        asm volatile("" ::: "memory");
#pragma unroll
        for (int mf = 0; mf < 2; ++mf) {
            const int hwl = w * 32 + mf * 16 + (lane & 15);
#pragma unroll
            for (int j = 0; j < 8; ++j) {
                int lc = ((lane >> 4) << 3) + j;
                float v = *(const float*)(xbuf + lc * 512 + hwl * 4);
                unsigned short h = f2bf(v);
                float hf = __uint_as_float(((unsigned)h) << 16);
                unsigned short l2 = f2bf(v - hf);
                Ah[mf][ci][j] = (short)h;
                Al[mf][ci][j] = (short)l2;
            }
        }
        __builtin_amdgcn_s_barrier();
        asm volatile("" ::: "memory");
        if (ci < 7) stage_xchunk(xbuf, xb, (ci + 1) * 32, hw0, w, lane);
    }

    float best[8], second[8];
    int bidx[8];
#pragma unroll
    for (int s = 0; s < 8; ++s) { best[s] = 1e30f; second[s] = 1e30f; bidx[s] = 0; }

    // per-lane swizzled LDS read base: row = lane&15 (code), co = (lane>>4)*16
    const int bro = (lane & 15) * 512 + ((((lane >> 4) << 4)) ^ ((lane & 15) << 4));

    // prefetch e-tiles 0,1
    stage_tile(smem, 0,     0, w, lane, eH, eL);
    stage_tile(smem, 16384, 1, w, lane, eH, eL);

    // eb_lds ds_writes must be visible across waves after the next barrier
    asm volatile("s_waitcnt lgkmcnt(0)" ::: "memory");

    int cur = 0;
#pragma unroll 1
    for (int nt = 0; nt < 32; ++nt) {
        // tile nt's 4 loads complete; tile nt+1's may stay in flight
        if (nt == 31) asm volatile("s_waitcnt vmcnt(0)" ::: "memory");
        else          asm volatile("s_waitcnt vmcnt(4)" ::: "memory");
        __builtin_amdgcn_s_barrier();
        asm volatile("" ::: "memory");

        // stage tile nt+2 into the buffer whose reads finished in iter nt-1
        if (nt < 30) {
            int nb = cur + 32768; if (nb >= LDS_TILES) nb -= LDS_TILES;
            stage_tile(smem, nb, nt + 2, w, lane, eH, eL);
        }

        const char* base = smem + cur;
        f32x4 aH0 = {0,0,0,0}, aH1 = {0,0,0,0};
        f32x4 aA0 = {0,0,0,0}, aA1 = {0,0,0,0};
        f32x4 aB0 = {0,0,0,0}, aB1 = {0,0,0,0};
#pragma unroll
        for (int cs = 0; cs < 8; ++cs) {
            int off = bro ^ (cs << 6);   // XOR-composable: co bits disjoint
            bf16x8 Bh = *reinterpret_cast<const bf16x8*>(base + off);
            bf16x8 Bl = *reinterpret_cast<const bf16x8*>(base + 8192 + off);
            aH0 = __builtin_amdgcn_mfma_f32_16x16x32_bf16(Ah[0][cs], Bh, aH0, 0, 0, 0);
            aH1 = __builtin_amdgcn_mfma_f32_16x16x32_bf16(Ah[1][cs], Bh, aH1, 0, 0, 0);
            aA0 = __builtin_amdgcn_mfma_f32_16x16x32_bf16(Al[0][cs], Bh, aA0, 0, 0, 0);
            aA1 = __builtin_amdgcn_mfma_f32_16x16x32_bf16(Al[1][cs], Bh, aA1, 0, 0, 0);
            aB0 = __builtin_amdgcn_mfma_f32_16x16x32_bf16(Ah[0][cs], Bl, aB0, 0, 0, 0);
            aB1 = __builtin_amdgcn_mfma_f32_16x16x32_bf16(Ah[1][cs], Bl, aB1, 0, 0, 0);
        }

        const int code = nt * 16 + (lane & 15);
        const float eb = eb_lds[code];   // LDS broadcast, no vmcnt traffic
#pragma unroll
        for (int mf = 0; mf < 2; ++mf) {
#pragma unroll
            for (int r = 0; r < 4; ++r) {
                float d = mf ? (aH1[r] + aA1[r] + aB1[r]) : (aH0[r] + aA0[r] + aB0[r]);
                float sc = fmaf(-2.f, d, eb);
                int slot = mf * 4 + r;
                if (sc < best[slot]) { second[slot] = best[slot]; best[slot] = sc; bidx[slot] = code; }
                else second[slot] = fminf(second[slot], sc);
            }
        }

        cur += 16384; if (cur == LDS_TILES) cur = 0;
    }

    // butterfly argmin over the 16 col-lanes (true top-2, first-idx ties)
#pragma unroll
    for (int m = 1; m < 16; m <<= 1) {
#pragma unroll
        for (int s = 0; s < 8; ++s) {
            float ob = __shfl_xor(best[s], m);
            float os = __shfl_xor(second[s], m);
            int   oi = __shfl_xor(bidx[s], m);
            bool take = (ob < best[s]) || (ob == best[s] && oi < bidx[s]);
            float ns = take ? fminf(best[s], os) : fminf(second[s], ob);
            if (take) { best[s] = ob; bidx[s] = oi; }
            second[s] = ns;
        }
    }

    if ((lane & 15) == 0) {
#pragma unroll
        for (int s = 0; s < 8; ++s) {
            int row_local = (s >> 2) * 16 + ((lane >> 4) << 2) + (s & 3);
            int r = w * 32 + row_local;
            idx_lds[r] = bidx[s];
            if (second[s] - best[s] < EPS_GAP) {
                int sl = atomicAdd(count, 1);
                if (sl < maxjobs) worklist[sl] = blockIdx.x * 128 + r;
            }
        }
    }
    __syncthreads();

    // fused gather: out[b,c,hw] = e[idx[j]][c]; float4 gathers from L2,
    // coalesced stores (lanes = consecutive j).
    {
        const int j = t & 127;
        const int half = t >> 7;
        const int code = idx_lds[j];
        const float4* e4 = reinterpret_cast<const float4*>(e);
        float* ob = out + (size_t)b * C_DIM * HW + hw0 + j;
#pragma unroll
        for (int i = 0; i < 32; ++i) {
            int c4 = half * 32 + i;
            float4 v = e4[(size_t)code * 64 + c4];
            ob[(size_t)(c4 * 4 + 0) * HW] = v.x;
            ob[(size_t)(c4 * 4 + 1) * HW] = v.y;
            ob[(size_t)(c4 * 4 + 2) * HW] = v.z;
            ob[(size_t)(c4 * 4 + 3) * HW] = v.w;
        }
    }
}

// ---- refine: exact fp64 argmin for flagged rows, rewrite out row ----
__global__ __launch_bounds__(64) void refine_kernel(const float* __restrict__ x,
                                                    const float* __restrict__ e,
                                                    float* __restrict__ out,
                                                    const int* __restrict__ worklist,
                                                    const int* __restrict__ count,
                                                    int maxjobs) {
    int njobs = *count;
    if (njobs > maxjobs) njobs = maxjobs;
    const int lane = threadIdx.x;

    for (int job = blockIdx.x; job < njobs; job += gridDim.x) {
        const int row = worklist[job];
        const int b = row >> 10;
        const int hw = row & (HW - 1);
        const float* xb = x + (size_t)b * C_DIM * HW + hw;

        double bestd = 1e300;
        int besti = K_EMB;
        for (int k = lane; k < K_EMB; k += 64) {
            const float* er = e + (size_t)k * C_DIM;
            double d = 0.0;
            for (int c = 0; c < C_DIM; ++c) {
                double diff = (double)xb[(size_t)c * HW] - (double)er[c];
                d = fma(diff, diff, d);
            }
            if (d < bestd || (d == bestd && k < besti)) { bestd = d; besti = k; }
        }
        for (int off = 32; off > 0; off >>= 1) {
            double od = __shfl_down(bestd, off);
            int    oi = __shfl_down(besti, off);
            if (od < bestd || (od == bestd && oi < besti)) { bestd = od; besti = oi; }
        }
        besti = __shfl(besti, 0);

        const float4 v = reinterpret_cast<const float4*>(e + (size_t)besti * C_DIM)[lane];
        float* ob = out + (size_t)b * C_DIM * HW + hw;
        ob[(size_t)(lane * 4 + 0) * HW] = v.x;
        ob[(size_t)(lane * 4 + 1) * HW] = v.y;
        ob[(size_t)(lane * 4 + 2) * HW] = v.z;
        ob[(size_t)(lane * 4 + 3) * HW] = v.w;
    }
}

extern "C" void kernel_launch(void* const* d_in, const int* in_sizes, int n_in,
                              void* d_out, int out_size, void* d_ws, size_t ws_size,
                              hipStream_t stream) {
    const float* x = (const float*)d_in[0];
    const float* e = (const float*)d_in[1];
    float* out = (float*)d_out;

    char* ws = (char*)d_ws;
    int* count = (int*)ws;
    float* ebias = (float*)(ws + WS_EBIAS);
    unsigned short* eH = (unsigned short*)(ws + WS_EH);
    unsigned short* eL = (unsigned short*)(ws + WS_EL);
    int* worklist = (int*)(ws + WS_WORK);
    int maxjobs = 0;
    if (ws_size > WS_WORK + 4) {
        size_t avail = (ws_size - WS_WORK) / 4;
        maxjobs = (int)(avail > 65536 ? 65536 : avail);
    }

    const int B = in_sizes[0] / (C_DIM * HW);

    hipLaunchKernelGGL(prep_e, dim3(K_EMB), dim3(256), 0, stream, e, eH, eL, ebias, count);
    hipLaunchKernelGGL(vq_mfma, dim3(B * 8), dim3(256), 0, stream,
                       x, eH, eL, ebias, e, out, count, worklist, maxjobs);
    hipLaunchKernelGGL(refine_kernel, dim3(512), dim3(64), 0, stream,
                       x, e, out, worklist, count, maxjobs);
}